// Round 24
// baseline (79.810 us; speedup 1.0000x reference)
//
#include <hip/hip_runtime.h>
#include <hip/hip_bf16.h>

typedef short short8 __attribute__((ext_vector_type(8)));
typedef float f32x4 __attribute__((ext_vector_type(4)));
typedef float f32x2 __attribute__((ext_vector_type(2)));
typedef unsigned short u16x4 __attribute__((ext_vector_type(4)));

#define D_ 256
#define K_ 1024
#define HW_ 1024
#define NROWS_ 32768
#define QELEMS 8388608  // 32*256*32*32
#define NBLK_ (NROWS_ / 64)

static __device__ __forceinline__ unsigned short to_bf16(float v) {
    __hip_bfloat16 h = __float2bfloat16(v);
    return *(unsigned short*)&h;
}

// ---------------- prep: fragment-major bf16 codebook ebf2[ct][dc][kg][col][8], enorm,
// zero counts/loss/done. grid 64 x 256.
__global__ __launch_bounds__(256) void vq_prep(const float* __restrict__ emb,
    unsigned short* __restrict__ ebf2, float* __restrict__ enorm,
    int* __restrict__ counts, double* __restrict__ loss_acc, int* __restrict__ done)
{
    __shared__ float part[256];
    const int ct = blockIdx.x, t = threadIdx.x;
    const int col = t & 15, s = t >> 4;          // s: 16-d segment 0..15
    const int k = ct * 16 + col;
    const f32x4* src = (const f32x4*)(emb + (size_t)k * D_ + s * 16);
    short8 f0, f1;
    float a = 0.f;
#pragma unroll
    for (int j = 0; j < 4; ++j) {
        f32x4 v = src[j];
#pragma unroll
        for (int q = 0; q < 4; ++q) {
            int idx = j * 4 + q;
            unsigned short h = to_bf16(v[q]);
            a = fmaf(v[q], v[q], a);
            if (idx < 8) f0[idx] = (short)h; else f1[idx - 8] = (short)h;
        }
    }
    part[t] = a;
    char* base = (char*)ebf2 + ct * 8192 + (s >> 1) * 1024 + ((s & 1) * 2) * 256 + col * 16;
    *(short8*)base = f0;
    *(short8*)(base + 256) = f1;
    __syncthreads();
    if (t < 16) {
        float s2 = 0.f;
#pragma unroll
        for (int j = 0; j < 16; ++j) s2 += part[t + 16 * j];
        enorm[ct * 16 + t] = s2;
    }
    if (ct < 4) counts[ct * 256 + t] = 0;
    if (ct == 0 && t == 0) { *loss_acc = 0.0; *done = 0; }
}

// ---------------- main: 64 rows/block, 8 waves. r17 schedule verbatim (barrier-free argmin
// loop, in-loop plain enc-zeros, full drains at epilogue) + fused scalars tail (done-counter).
__global__ __launch_bounds__(512, 4) void vq_main(
    const float* __restrict__ x, const float* __restrict__ emb,
    const unsigned short* __restrict__ ebf2, const float* __restrict__ enorm,
    int* __restrict__ counts, double* __restrict__ loss_acc, int* __restrict__ done,
    float* __restrict__ out)
{
    __shared__ char smem[65536];              // xs [0,32K) -> q_lds 64K in epilogue
    __shared__ float xn[64][9];
    __shared__ float rminv[64][4];
    __shared__ int   rmini[64][4];
    __shared__ int   bestsh[64];
    __shared__ double sred2[8];
    __shared__ int lastflag;

    char* xs = smem;

    const int t = threadIdx.x;
    const int n0 = blockIdx.x * 64;
    const int b = n0 >> 10;
    const int hw0 = n0 & 1023;
    const float* xbase = x + (size_t)b * (D_ * HW_) + hw0;

    // ---- stage x -> fragment-major bf16 LDS: xs[rtile][dc][kg][col][8]
    {
        const int rt = t & 15, r0 = rt * 4;
        const int dg = t >> 4;          // 0..31
        float xp[4] = {0.f, 0.f, 0.f, 0.f};
#pragma unroll
        for (int m = 0; m < 2; ++m) {
            int d0 = (dg + 32 * m) * 4;
            f32x4 c[4];
#pragma unroll
            for (int q = 0; q < 4; ++q)
                c[q] = *(const f32x4*)(xbase + (size_t)(d0 + q) * HW_ + r0);
            const int dc = d0 >> 5, kg = (d0 >> 3) & 3, off = (d0 & 7) * 2;
#pragma unroll
            for (int i = 0; i < 4; ++i) {
                u16x4 pk;
                pk[0] = to_bf16(c[0][i]); pk[1] = to_bf16(c[1][i]);
                pk[2] = to_bf16(c[2][i]); pk[3] = to_bf16(c[3][i]);
                xp[i] = fmaf(c[0][i], c[0][i], xp[i]);
                xp[i] = fmaf(c[1][i], c[1][i], xp[i]);
                xp[i] = fmaf(c[2][i], c[2][i], xp[i]);
                xp[i] = fmaf(c[3][i], c[3][i], xp[i]);
                int r = r0 + i;
                int byte = ((r >> 4) << 13) + (dc << 10) + (kg << 8) + ((r & 15) << 4) + off;
                *(u16x4*)(xs + byte) = pk;
            }
        }
#pragma unroll
        for (int i = 0; i < 4; ++i) {
            xp[i] += __shfl_down(xp[i], 32);
            xp[i] += __shfl_down(xp[i], 16);
        }
        if ((t & 48) == 0) {
            int w0 = t >> 6;
#pragma unroll
            for (int i = 0; i < 4; ++i) xn[r0 + i][w0] = xp[i];
        }
    }

    const int lane = t & 63;
    const int w = t >> 6;          // 0..7
    const int rh = w & 1;          // row half
    const int cq = w >> 1;         // 16-code tile within 64-chunk
    const int col = lane & 15;
    const char* eb = (const char*)ebf2;

    __syncthreads();               // xs resident

    // ---- A fragments: lane-linear reads (conflict-free)
    short8 areg[2][8];
#pragma unroll
    for (int rt = 0; rt < 2; ++rt) {
        const char* ab = xs + ((rh * 2 + rt) << 13);
#pragma unroll
        for (int dc = 0; dc < 8; ++dc)
            areg[rt][dc] = *(const short8*)(ab + dc * 1024 + lane * 16);
    }

    float v1[8]; int i1[8];
#pragma unroll
    for (int s = 0; s < 8; ++s) { v1[s] = 3.4e38f; i1[s] = 0x7fffffff; }

    f32x2* ezw = (f32x2*)(out + 8388610 + (size_t)(n0 + w * 8) * 1024);
    const f32x2 zz = {0.f, 0.f};

    // ---- barrier-free argmin loop: 8 coalesced 1KB B-loads + 16 MFMA + 4 enc-zero stores
    for (int cc = 0; cc < 16; ++cc) {
        const char* tb = eb + cc * 32768 + (cq << 13);
        short8 bf[8];
#pragma unroll
        for (int dc = 0; dc < 8; ++dc)
            bf[dc] = *(const short8*)(tb + dc * 1024 + lane * 16);
        f32x4 acc0 = {0.f, 0.f, 0.f, 0.f};
        f32x4 acc1 = {0.f, 0.f, 0.f, 0.f};
#pragma unroll
        for (int dc = 0; dc < 8; ++dc) {
            acc0 = __builtin_amdgcn_mfma_f32_16x16x32_bf16(areg[0][dc], bf[dc], acc0, 0, 0, 0);
            acc1 = __builtin_amdgcn_mfma_f32_16x16x32_bf16(areg[1][dc], bf[dc], acc1, 0, 0, 0);
        }
        const int code = cc * 64 + cq * 16 + col;
        const float bn = enorm[code];          // L1-cached
#pragma unroll
        for (int r = 0; r < 4; ++r) {
            float dv = fmaf(-2.f, acc0[r], bn);
            if (dv < v1[r]) { v1[r] = dv; i1[r] = code; }
            float dw = fmaf(-2.f, acc1[r], bn);
            if (dw < v1[4 + r]) { v1[4 + r] = dw; i1[4 + r] = code; }
        }
        // enc-zero slice for this chunk: 4 x 512B contiguous plain stores
        f32x2* ez = ezw + cc * 256;
#pragma unroll
        for (int j = 0; j < 4; ++j) ez[j * 64 + lane] = zz;
    }

    // ---- butterfly min over 16 cols (lane bits 0-3), tie -> lower index
#pragma unroll
    for (int mask = 1; mask < 16; mask <<= 1) {
#pragma unroll
        for (int s = 0; s < 8; ++s) {
            float ov = __shfl_xor(v1[s], mask);
            int oi = __shfl_xor(i1[s], mask);
            if (ov < v1[s] || (ov == v1[s] && oi < i1[s])) { v1[s] = ov; i1[s] = oi; }
        }
    }
    {
        const int kg = lane >> 4;
        if (col == 0) {
#pragma unroll
            for (int s = 0; s < 8; ++s) {
                int rt = s >> 2, r = s & 3;
                int row = rh * 32 + rt * 16 + kg * 4 + r;
                rminv[row][cq] = v1[s];
                rmini[row][cq] = i1[s];
            }
        }
    }
    __syncthreads();

    // ---- finalize (wave 0): pick across 4 code tiles, counts/loss/bestsh
    if (t < 64) {
        float dmin = rminv[t][0]; int best = rmini[t][0];
#pragma unroll
        for (int g = 1; g < 4; ++g) {
            float cv = rminv[t][g]; int ci = rmini[t][g];
            if (cv < dmin || (cv == dmin && ci < best)) { dmin = cv; best = ci; }
        }
        bestsh[t] = best;
        atomicAdd(&counts[best], 1);
        float s = 0.f;
#pragma unroll
        for (int g = 0; g < 8; ++g) s += xn[t][g];
        float lrow = dmin + s;     // |x-e|^2 = (|e|^2 - 2x.e) + |x|^2
        for (int o = 32; o > 0; o >>= 1) lrow += __shfl_down(lrow, o);
        if (t == 0) atomicAdd(loss_acc, (double)lrow);
    }
    __syncthreads();

    // ---- gather chosen fp32 rows into q_lds[64][256] with XOR(d, r&31) permutation
    {
        int r = w * 8 + (lane >> 3);
        int c = lane & 7;
        const f32x4* src4 = (const f32x4*)emb + (size_t)bestsh[r] * 64;
        float* q = (float*)smem + r * 256;
        int xr = r & 31;
#pragma unroll
        for (int j = 0; j < 8; ++j) {
            f32x4 v = src4[8 * j + c];
#pragma unroll
            for (int kq = 0; kq < 4; ++kq) {
                int d = 4 * (8 * j + c) + kq;
                q[d ^ xr] = v[kq];
            }
        }
    }
    __syncthreads();

    // ---- write quantized out[b][d][hw0+hwr] (wave = 256B contiguous per d)
    {
        const int hwr = t & 63;
        const int dq = t >> 6;
        float* outq = out + 1 + (size_t)b * (D_ * HW_) + hw0 + hwr;
        const float* q = (const float*)smem + hwr * 256;
        int xr = hwr & 31;
#pragma unroll
        for (int dd = 0; dd < 32; ++dd) {
            int d = dq + dd * 8;
            outq[(size_t)d * HW_] = q[d ^ xr];
        }
    }
    // ---- encodings 1.0 poke (in-loop zeros drained by the vmcnt(0) barriers above)
    if (t < 64) out[8388610 + (size_t)(n0 + t) * 1024 + bestsh[t]] = 1.0f;

    // ---- last block computes loss scalar + perplexity (replaces vq_fin launch)
    if (t == 0) {
        __threadfence();
        int old = atomicAdd(done, 1);
        lastflag = (old == NBLK_ - 1) ? 1 : 0;
    }
    __syncthreads();
    if (lastflag) {
        double s = 0.0;
#pragma unroll
        for (int j = 0; j < 2; ++j) {
            int k = t * 2 + j;
            int cnt = __hip_atomic_load(&counts[k], __ATOMIC_RELAXED, __HIP_MEMORY_SCOPE_AGENT);
            double p = (double)cnt / 32768.0;
            s += p * log(p + 1e-10);
        }
        for (int o = 32; o > 0; o >>= 1) s += __shfl_down(s, o);
        if (lane == 0) sred2[w] = s;
        __syncthreads();
        if (t == 0) {
            double tot = 0.0;
#pragma unroll
            for (int g = 0; g < 8; ++g) tot += sred2[g];
            double lw = __hip_atomic_load(loss_acc, __ATOMIC_RELAXED, __HIP_MEMORY_SCOPE_AGENT);
            out[0] = (float)(1.25 * lw / (double)QELEMS);
            out[8388609] = (float)exp(-tot);
        }
    }
}

extern "C" void kernel_launch(void* const* d_in, const int* in_sizes, int n_in,
                              void* d_out, int out_size, void* d_ws, size_t ws_size,
                              hipStream_t stream)
{
    const float* x = (const float*)d_in[0];
    const float* emb = (const float*)d_in[1];
    char* ws = (char*)d_ws;
    unsigned short* ebf2 = (unsigned short*)(ws);                // 512 KB fragment-major
    float* enorm = (float*)(ws + 524288);                        // 4 KB
    int* counts = (int*)(ws + 528384);                           // 4 KB
    double* lacc = (double*)(ws + 532480);                       // 8 B
    int* done = (int*)(ws + 532488);                             // 4 B
    float* out = (float*)d_out;

    vq_prep<<<64, 256, 0, stream>>>(emb, ebf2, enorm, counts, lacc, done);
    vq_main<<<NBLK_, 512, 0, stream>>>(x, emb, ebf2, enorm, counts, lacc, done, out);
}

// Round 25
// 62.401 us; speedup vs baseline: 1.2790x; 1.2790x over previous
//
#include <hip/hip_runtime.h>
#include <hip/hip_bf16.h>

typedef short short8 __attribute__((ext_vector_type(8)));
typedef float f32x4 __attribute__((ext_vector_type(4)));
typedef float f32x2 __attribute__((ext_vector_type(2)));
typedef unsigned short u16x4 __attribute__((ext_vector_type(4)));

#define D_ 256
#define K_ 1024
#define HW_ 1024
#define NROWS_ 32768
#define QELEMS 8388608  // 32*256*32*32
#define NBLK_ (NROWS_ / 64)

static __device__ __forceinline__ unsigned short to_bf16(float v) {
    __hip_bfloat16 h = __float2bfloat16(v);
    return *(unsigned short*)&h;
}

// ---------------- prep: fragment-major bf16 codebook ebf2[ct][dc][kg][col][8], enorm,
// zero counts/loss. grid 64 x 256.
__global__ __launch_bounds__(256) void vq_prep(const float* __restrict__ emb,
    unsigned short* __restrict__ ebf2, float* __restrict__ enorm,
    int* __restrict__ counts, double* __restrict__ loss_acc)
{
    __shared__ float part[256];
    const int ct = blockIdx.x, t = threadIdx.x;
    const int col = t & 15, s = t >> 4;          // s: 16-d segment 0..15
    const int k = ct * 16 + col;
    const f32x4* src = (const f32x4*)(emb + (size_t)k * D_ + s * 16);
    short8 f0, f1;
    float a = 0.f;
#pragma unroll
    for (int j = 0; j < 4; ++j) {
        f32x4 v = src[j];
#pragma unroll
        for (int q = 0; q < 4; ++q) {
            int idx = j * 4 + q;
            unsigned short h = to_bf16(v[q]);
            a = fmaf(v[q], v[q], a);
            if (idx < 8) f0[idx] = (short)h; else f1[idx - 8] = (short)h;
        }
    }
    part[t] = a;
    // d-range s*16.. : dc = s>>1, kg0 = (s&1)*2, next 8 d -> kg0+1
    char* base = (char*)ebf2 + ct * 8192 + (s >> 1) * 1024 + ((s & 1) * 2) * 256 + col * 16;
    *(short8*)base = f0;
    *(short8*)(base + 256) = f1;
    __syncthreads();
    if (t < 16) {
        float s2 = 0.f;
#pragma unroll
        for (int j = 0; j < 16; ++j) s2 += part[t + 16 * j];
        enorm[ct * 16 + t] = s2;
    }
    if (ct < 4) counts[ct * 256 + t] = 0;
    if (ct == 0 && t == 0) *loss_acc = 0.0;
}

// ---------------- main: 64 rows/block, 8 waves. Barrier-free argmin loop: B-fragments
// streamed direct from L2-resident fragment-major codebook (coalesced 1KB/wave loads),
// enc-zero stores riding in-loop. Fused loss/scatter/enc epilogue.
__global__ __launch_bounds__(512, 4) void vq_main(
    const float* __restrict__ x, const float* __restrict__ emb,
    const unsigned short* __restrict__ ebf2, const float* __restrict__ enorm,
    int* __restrict__ counts, double* __restrict__ loss_acc, float* __restrict__ out)
{
    __shared__ char smem[65536];              // xs [0,32K) -> q_lds 64K in epilogue
    __shared__ float xn[64][9];
    __shared__ float rminv[64][4];
    __shared__ int   rmini[64][4];
    __shared__ int   bestsh[64];

    char* xs = smem;

    const int t = threadIdx.x;
    const int n0 = blockIdx.x * 64;
    const int b = n0 >> 10;
    const int hw0 = n0 & 1023;
    const float* xbase = x + (size_t)b * (D_ * HW_) + hw0;

    // ---- stage x -> fragment-major bf16 LDS: xs[rtile][dc][kg][col][8]
    {
        const int rt = t & 15, r0 = rt * 4;
        const int dg = t >> 4;          // 0..31
        float xp[4] = {0.f, 0.f, 0.f, 0.f};
#pragma unroll
        for (int m = 0; m < 2; ++m) {
            int d0 = (dg + 32 * m) * 4;
            f32x4 c[4];
#pragma unroll
            for (int q = 0; q < 4; ++q)
                c[q] = *(const f32x4*)(xbase + (size_t)(d0 + q) * HW_ + r0);
            const int dc = d0 >> 5, kg = (d0 >> 3) & 3, off = (d0 & 7) * 2;
#pragma unroll
            for (int i = 0; i < 4; ++i) {
                u16x4 pk;
                pk[0] = to_bf16(c[0][i]); pk[1] = to_bf16(c[1][i]);
                pk[2] = to_bf16(c[2][i]); pk[3] = to_bf16(c[3][i]);
                xp[i] = fmaf(c[0][i], c[0][i], xp[i]);
                xp[i] = fmaf(c[1][i], c[1][i], xp[i]);
                xp[i] = fmaf(c[2][i], c[2][i], xp[i]);
                xp[i] = fmaf(c[3][i], c[3][i], xp[i]);
                int r = r0 + i;
                int byte = ((r >> 4) << 13) + (dc << 10) + (kg << 8) + ((r & 15) << 4) + off;
                *(u16x4*)(xs + byte) = pk;
            }
        }
#pragma unroll
        for (int i = 0; i < 4; ++i) {
            xp[i] += __shfl_down(xp[i], 32);
            xp[i] += __shfl_down(xp[i], 16);
        }
        if ((t & 48) == 0) {
            int w0 = t >> 6;
#pragma unroll
            for (int i = 0; i < 4; ++i) xn[r0 + i][w0] = xp[i];
        }
    }

    const int lane = t & 63;
    const int w = t >> 6;          // 0..7
    const int rh = w & 1;          // row half
    const int cq = w >> 1;         // 16-code tile within 64-chunk
    const int col = lane & 15;
    const char* eb = (const char*)ebf2;

    __syncthreads();               // xs resident

    // ---- A fragments: lane-linear reads (conflict-free)
    short8 areg[2][8];
#pragma unroll
    for (int rt = 0; rt < 2; ++rt) {
        const char* ab = xs + ((rh * 2 + rt) << 13);
#pragma unroll
        for (int dc = 0; dc < 8; ++dc)
            areg[rt][dc] = *(const short8*)(ab + dc * 1024 + lane * 16);
    }

    float v1[8]; int i1[8];
#pragma unroll
    for (int s = 0; s < 8; ++s) { v1[s] = 3.4e38f; i1[s] = 0x7fffffff; }

    f32x2* ezw = (f32x2*)(out + 8388610 + (size_t)(n0 + w * 8) * 1024);
    const f32x2 zz = {0.f, 0.f};

    // ---- barrier-free argmin loop: 8 coalesced 1KB B-loads + 16 MFMA + 4 enc-zero stores
    for (int cc = 0; cc < 16; ++cc) {
        const char* tb = eb + cc * 32768 + (cq << 13);
        short8 bf[8];
#pragma unroll
        for (int dc = 0; dc < 8; ++dc)
            bf[dc] = *(const short8*)(tb + dc * 1024 + lane * 16);
        f32x4 acc0 = {0.f, 0.f, 0.f, 0.f};
        f32x4 acc1 = {0.f, 0.f, 0.f, 0.f};
#pragma unroll
        for (int dc = 0; dc < 8; ++dc) {
            acc0 = __builtin_amdgcn_mfma_f32_16x16x32_bf16(areg[0][dc], bf[dc], acc0, 0, 0, 0);
            acc1 = __builtin_amdgcn_mfma_f32_16x16x32_bf16(areg[1][dc], bf[dc], acc1, 0, 0, 0);
        }
        const int code = cc * 64 + cq * 16 + col;
        const float bn = enorm[code];          // L1-cached
#pragma unroll
        for (int r = 0; r < 4; ++r) {
            float dv = fmaf(-2.f, acc0[r], bn);
            if (dv < v1[r]) { v1[r] = dv; i1[r] = code; }
            float dw = fmaf(-2.f, acc1[r], bn);
            if (dw < v1[4 + r]) { v1[4 + r] = dw; i1[4 + r] = code; }
        }
        // enc-zero slice for this chunk: 4 x 512B contiguous stores, no barrier to poison
        f32x2* ez = ezw + cc * 256;
#pragma unroll
        for (int j = 0; j < 4; ++j) ez[j * 64 + lane] = zz;
    }

    // ---- butterfly min over 16 cols (lane bits 0-3), tie -> lower index
#pragma unroll
    for (int mask = 1; mask < 16; mask <<= 1) {
#pragma unroll
        for (int s = 0; s < 8; ++s) {
            float ov = __shfl_xor(v1[s], mask);
            int oi = __shfl_xor(i1[s], mask);
            if (ov < v1[s] || (ov == v1[s] && oi < i1[s])) { v1[s] = ov; i1[s] = oi; }
        }
    }
    {
        const int kg = lane >> 4;
        if (col == 0) {
#pragma unroll
            for (int s = 0; s < 8; ++s) {
                int rt = s >> 2, r = s & 3;
                int row = rh * 32 + rt * 16 + kg * 4 + r;
                rminv[row][cq] = v1[s];
                rmini[row][cq] = i1[s];
            }
        }
    }
    __syncthreads();

    // ---- finalize (wave 0): pick across 4 code tiles, counts/loss/bestsh
    if (t < 64) {
        float dmin = rminv[t][0]; int best = rmini[t][0];
#pragma unroll
        for (int g = 1; g < 4; ++g) {
            float cv = rminv[t][g]; int ci = rmini[t][g];
            if (cv < dmin || (cv == dmin && ci < best)) { dmin = cv; best = ci; }
        }
        bestsh[t] = best;
        atomicAdd(&counts[best], 1);
        float s = 0.f;
#pragma unroll
        for (int g = 0; g < 8; ++g) s += xn[t][g];
        float lrow = dmin + s;     // |x-e|^2 = (|e|^2 - 2x.e) + |x|^2
        for (int o = 32; o > 0; o >>= 1) lrow += __shfl_down(lrow, o);
        if (t == 0) atomicAdd(loss_acc, (double)lrow);
    }
    __syncthreads();

    // ---- gather chosen fp32 rows into q_lds[64][256] with XOR(d, r&31) permutation
    {
        int r = w * 8 + (lane >> 3);
        int c = lane & 7;
        const f32x4* src4 = (const f32x4*)emb + (size_t)bestsh[r] * 64;
        float* q = (float*)smem + r * 256;
        int xr = r & 31;
#pragma unroll
        for (int j = 0; j < 8; ++j) {
            f32x4 v = src4[8 * j + c];
#pragma unroll
            for (int kq = 0; kq < 4; ++kq) {
                int d = 4 * (8 * j + c) + kq;
                q[d ^ xr] = v[kq];
            }
        }
    }
    __syncthreads();

    // ---- write quantized out[b][d][hw0+hwr] (wave = 256B contiguous per d)
    {
        const int hwr = t & 63;
        const int dq = t >> 6;
        float* outq = out + 1 + (size_t)b * (D_ * HW_) + hw0 + hwr;
        const float* q = (const float*)smem + hwr * 256;
        int xr = hwr & 31;
#pragma unroll
        for (int dd = 0; dd < 32; ++dd) {
            int d = dq + dd * 8;
            outq[(size_t)d * HW_] = q[d ^ xr];
        }
    }
    // ---- encodings 1.0 poke (in-loop zeros drained by the vmcnt(0) in barriers above)
    if (t < 64) out[8388610 + (size_t)(n0 + t) * 1024 + bestsh[t]] = 1.0f;
}

// ---------------- finalize: loss scalar + perplexity
__global__ __launch_bounds__(256) void vq_fin(const int* __restrict__ counts,
    const double* __restrict__ loss_acc, float* __restrict__ d_out)
{
    int t = threadIdx.x;
    double s = 0.0;
    for (int k = t; k < K_; k += 256) {
        double p = (double)counts[k] / 32768.0;
        s += p * log(p + 1e-10);
    }
    for (int o = 32; o > 0; o >>= 1) s += __shfl_down(s, o);
    __shared__ double sred[4];
    if ((t & 63) == 0) sred[t >> 6] = s;
    __syncthreads();
    if (t == 0) {
        double tot = sred[0] + sred[1] + sred[2] + sred[3];
        d_out[0] = (float)(1.25 * (*loss_acc) / (double)QELEMS);
        d_out[8388609] = (float)exp(-tot);
    }
}

extern "C" void kernel_launch(void* const* d_in, const int* in_sizes, int n_in,
                              void* d_out, int out_size, void* d_ws, size_t ws_size,
                              hipStream_t stream)
{
    const float* x = (const float*)d_in[0];
    const float* emb = (const float*)d_in[1];
    char* ws = (char*)d_ws;
    unsigned short* ebf2 = (unsigned short*)(ws);                // 512 KB fragment-major
    float* enorm = (float*)(ws + 524288);                        // 4 KB
    int* counts = (int*)(ws + 528384);                           // 4 KB
    double* lacc = (double*)(ws + 532480);                       // 8 B
    float* out = (float*)d_out;

    vq_prep<<<64, 256, 0, stream>>>(emb, ebf2, enorm, counts, lacc);
    vq_main<<<NBLK_, 512, 0, stream>>>(x, emb, ebf2, enorm, counts, lacc, out);
    vq_fin<<<1, 256, 0, stream>>>(counts, lacc, out);
}